// Round 1
// baseline (647.149 us; speedup 1.0000x reference)
//
#include <hip/hip_runtime.h>
#include <hip/hip_bf16.h>
#include <cstdint>

#define HD 1024
#define ID 4096
#define NE 8
#define NTOK 4096
#define NASS 8192

typedef unsigned short u16;
typedef __attribute__((ext_vector_type(8))) __bf16 bf16x8;
typedef __attribute__((ext_vector_type(4))) float f32x4;

__device__ __forceinline__ void async16(void* lds, const void* g) {
  __builtin_amdgcn_global_load_lds(
      (const __attribute__((address_space(1))) uint32_t*)g,
      (__attribute__((address_space(3))) uint32_t*)lds, 16, 0, 0);
}

__device__ __forceinline__ u16 f2b(float f) {
  __bf16 h = (__bf16)f;
  return __builtin_bit_cast(u16, h);
}

__device__ __forceinline__ bf16x8 cvt8(const float* p) {
  const float4* q = (const float4*)p;
  float4 a = q[0], b = q[1];
  bf16x8 v;
  v[0] = (__bf16)a.x; v[1] = (__bf16)a.y; v[2] = (__bf16)a.z; v[3] = (__bf16)a.w;
  v[4] = (__bf16)b.x; v[5] = (__bf16)b.y; v[6] = (__bf16)b.z; v[7] = (__bf16)b.w;
  return v;
}

// ---- prep: x fp32 -> bf16, zero out, zero counters ----
__global__ void k_prep(const float* __restrict__ x, u16* __restrict__ xb,
                       float* __restrict__ out, int* __restrict__ counts,
                       int* __restrict__ cursors) {
  int gid = blockIdx.x * 256 + threadIdx.x;
  size_t i8 = (size_t)gid * 8;
  const float4* xp = (const float4*)(x + i8);
  float4 a = xp[0], b = xp[1];
  bf16x8 v;
  v[0] = (__bf16)a.x; v[1] = (__bf16)a.y; v[2] = (__bf16)a.z; v[3] = (__bf16)a.w;
  v[4] = (__bf16)b.x; v[5] = (__bf16)b.y; v[6] = (__bf16)b.z; v[7] = (__bf16)b.w;
  *(bf16x8*)(xb + i8) = v;
  float4 z = {0.f, 0.f, 0.f, 0.f};
  float4* op = (float4*)(out + i8);
  op[0] = z; op[1] = z;
  if (gid < NE) { counts[gid] = 0; cursors[gid] = 0; }
}

__global__ void k_count(const int* __restrict__ eidx, int* __restrict__ counts) {
  int tid = blockIdx.x * 256 + threadIdx.x;
  if (tid < NASS) atomicAdd(&counts[eidx[tid]], 1);
}

__global__ void k_scan(const int* __restrict__ counts, int* __restrict__ offsets) {
  if (threadIdx.x == 0 && blockIdx.x == 0) {
    int s = 0;
    for (int e = 0; e < NE; ++e) { offsets[e] = s; s += counts[e]; }
    offsets[NE] = s;
  }
}

__global__ void k_place(const int* __restrict__ eidx, const float* __restrict__ ewt,
                        const int* __restrict__ offsets, int* __restrict__ cursors,
                        int* __restrict__ tokl, float* __restrict__ wtl) {
  int tid = blockIdx.x * 256 + threadIdx.x;
  if (tid < NASS) {
    int e = eidx[tid];
    int pos = atomicAdd(&cursors[e], 1);
    int row = offsets[e] + pos;
    tokl[row] = tid >> 1;     // token index
    wtl[row] = ewt[tid];
  }
}

// ---- GEMM1: interm[row, :] = silu(X @ G^T) * (X @ U^T), grouped by expert ----
// tile: BM=128 (rows) x BN=64 (I cols) x BK=64, 4 waves (2x2), dual accumulators
__global__ __launch_bounds__(256) void k_gemm1(
    const u16* __restrict__ xb, const float* __restrict__ gate,
    const float* __restrict__ up, const int* __restrict__ offsets,
    const int* __restrict__ tokl, u16* __restrict__ interm) {
  const int e = blockIdx.z;
  const int offs = offsets[e];
  const int Me = offsets[e + 1] - offs;
  const int m0 = blockIdx.y * 128;
  if (m0 >= Me) return;
  const int n0 = blockIdx.x * 64;
  const int t = threadIdx.x, lane = t & 63, wv = t >> 6;
  const int wm = wv & 1, wn = wv >> 1;

  __shared__ __align__(16) u16 As[128 * 64];
  __shared__ __align__(16) u16 Bg[64 * 64];
  __shared__ __align__(16) u16 Bu[64 * 64];

  const u16* asrc[4];
#pragma unroll
  for (int p = 0; p < 4; ++p) {
    int c = p * 256 + t;
    int r = c >> 3, c8 = c & 7;
    int row = m0 + r; if (row > Me - 1) row = Me - 1;
    asrc[p] = xb + (size_t)tokl[offs + row] * HD + c8 * 8;
  }
  const float *gsrc[2], *usrc[2];
#pragma unroll
  for (int q = 0; q < 2; ++q) {
    int c = q * 256 + t;
    int r = c >> 3, c8 = c & 7;
    size_t boff = ((size_t)e * ID + n0 + r) * HD + c8 * 8;
    gsrc[q] = gate + boff;
    usrc[q] = up + boff;
  }

  f32x4 accg[4][2], accu[4][2];
#pragma unroll
  for (int mi = 0; mi < 4; ++mi)
#pragma unroll
    for (int ni = 0; ni < 2; ++ni) {
      accg[mi][ni] = (f32x4){0.f, 0.f, 0.f, 0.f};
      accu[mi][ni] = (f32x4){0.f, 0.f, 0.f, 0.f};
    }

  const int lrow = lane & 15, lk = (lane >> 4) * 8;
#pragma unroll 1
  for (int ks = 0; ks < HD / 64; ++ks) {
    __syncthreads();
#pragma unroll
    for (int p = 0; p < 4; ++p)
      async16((char*)As + (p * 256 + wv * 64) * 16, asrc[p]);
#pragma unroll
    for (int q = 0; q < 2; ++q) {
      bf16x8 vg = cvt8(gsrc[q]);
      bf16x8 vu = cvt8(usrc[q]);
      *(bf16x8*)((char*)Bg + (q * 256 + t) * 16) = vg;
      *(bf16x8*)((char*)Bu + (q * 256 + t) * 16) = vu;
    }
    __syncthreads();
#pragma unroll
    for (int kk = 0; kk < 2; ++kk) {
      bf16x8 af[4], bg[2], bu[2];
#pragma unroll
      for (int mi = 0; mi < 4; ++mi)
        af[mi] = *(const bf16x8*)&As[(wm * 64 + mi * 16 + lrow) * 64 + kk * 32 + lk];
#pragma unroll
      for (int ni = 0; ni < 2; ++ni) {
        bg[ni] = *(const bf16x8*)&Bg[(wn * 32 + ni * 16 + lrow) * 64 + kk * 32 + lk];
        bu[ni] = *(const bf16x8*)&Bu[(wn * 32 + ni * 16 + lrow) * 64 + kk * 32 + lk];
      }
#pragma unroll
      for (int mi = 0; mi < 4; ++mi)
#pragma unroll
        for (int ni = 0; ni < 2; ++ni) {
          accg[mi][ni] = __builtin_amdgcn_mfma_f32_16x16x32_bf16(af[mi], bg[ni], accg[mi][ni], 0, 0, 0);
          accu[mi][ni] = __builtin_amdgcn_mfma_f32_16x16x32_bf16(af[mi], bu[ni], accu[mi][ni], 0, 0, 0);
        }
    }
#pragma unroll
    for (int p = 0; p < 4; ++p) asrc[p] += 64;
    gsrc[0] += 64; gsrc[1] += 64; usrc[0] += 64; usrc[1] += 64;
  }

#pragma unroll
  for (int mi = 0; mi < 4; ++mi) {
    int rb = wm * 64 + mi * 16 + (lane >> 4) * 4;
#pragma unroll
    for (int ni = 0; ni < 2; ++ni) {
      int col = n0 + wn * 32 + ni * 16 + (lane & 15);
#pragma unroll
      for (int j = 0; j < 4; ++j) {
        int row = m0 + rb + j;
        if (row < Me) {
          float g = accg[mi][ni][j], u = accu[mi][ni][j];
          float s = g / (1.f + __expf(-g));
          interm[(size_t)(offs + row) * ID + col] = f2b(s * u);
        }
      }
    }
  }
}

// ---- GEMM2: out[token, :] += wt * (interm @ D^T), grouped by expert ----
__global__ __launch_bounds__(256) void k_gemm2(
    const u16* __restrict__ interm, const float* __restrict__ down,
    const int* __restrict__ offsets, const int* __restrict__ tokl,
    const float* __restrict__ wtl, float* __restrict__ out) {
  const int e = blockIdx.z;
  const int offs = offsets[e];
  const int Me = offsets[e + 1] - offs;
  const int m0 = blockIdx.y * 128;
  if (m0 >= Me) return;
  const int n0 = blockIdx.x * 64;
  const int t = threadIdx.x, lane = t & 63, wv = t >> 6;
  const int wm = wv & 1, wn = wv >> 1;

  __shared__ __align__(16) u16 As[128 * 64];
  __shared__ __align__(16) u16 Bs[64 * 64];

  const u16* asrc[4];
#pragma unroll
  for (int p = 0; p < 4; ++p) {
    int c = p * 256 + t;
    int r = c >> 3, c8 = c & 7;
    int row = m0 + r; if (row > Me - 1) row = Me - 1;
    asrc[p] = interm + (size_t)(offs + row) * ID + c8 * 8;
  }
  const float* bsrc[2];
#pragma unroll
  for (int q = 0; q < 2; ++q) {
    int c = q * 256 + t;
    int r = c >> 3, c8 = c & 7;
    bsrc[q] = down + ((size_t)e * HD + n0 + r) * ID + c8 * 8;
  }

  f32x4 acc[4][2];
#pragma unroll
  for (int mi = 0; mi < 4; ++mi)
#pragma unroll
    for (int ni = 0; ni < 2; ++ni) acc[mi][ni] = (f32x4){0.f, 0.f, 0.f, 0.f};

  const int lrow = lane & 15, lk = (lane >> 4) * 8;
#pragma unroll 1
  for (int ks = 0; ks < ID / 64; ++ks) {
    __syncthreads();
#pragma unroll
    for (int p = 0; p < 4; ++p)
      async16((char*)As + (p * 256 + wv * 64) * 16, asrc[p]);
#pragma unroll
    for (int q = 0; q < 2; ++q)
      *(bf16x8*)((char*)Bs + (q * 256 + t) * 16) = cvt8(bsrc[q]);
    __syncthreads();
#pragma unroll
    for (int kk = 0; kk < 2; ++kk) {
      bf16x8 af[4], bfr[2];
#pragma unroll
      for (int mi = 0; mi < 4; ++mi)
        af[mi] = *(const bf16x8*)&As[(wm * 64 + mi * 16 + lrow) * 64 + kk * 32 + lk];
#pragma unroll
      for (int ni = 0; ni < 2; ++ni)
        bfr[ni] = *(const bf16x8*)&Bs[(wn * 32 + ni * 16 + lrow) * 64 + kk * 32 + lk];
#pragma unroll
      for (int mi = 0; mi < 4; ++mi)
#pragma unroll
        for (int ni = 0; ni < 2; ++ni)
          acc[mi][ni] = __builtin_amdgcn_mfma_f32_16x16x32_bf16(af[mi], bfr[ni], acc[mi][ni], 0, 0, 0);
    }
#pragma unroll
    for (int p = 0; p < 4; ++p) asrc[p] += 64;
    bsrc[0] += 64; bsrc[1] += 64;
  }

#pragma unroll
  for (int mi = 0; mi < 4; ++mi) {
    int rb = wm * 64 + mi * 16 + (lane >> 4) * 4;
#pragma unroll
    for (int ni = 0; ni < 2; ++ni) {
      int col = n0 + wn * 32 + ni * 16 + (lane & 15);
#pragma unroll
      for (int j = 0; j < 4; ++j) {
        int row = m0 + rb + j;
        if (row < Me) {
          int grow = offs + row;
          float w = wtl[grow];
          int token = tokl[grow];
          atomicAdd(out + (size_t)token * HD + col, w * acc[mi][ni][j]);
        }
      }
    }
  }
}

extern "C" void kernel_launch(void* const* d_in, const int* in_sizes, int n_in,
                              void* d_out, int out_size, void* d_ws, size_t ws_size,
                              hipStream_t stream) {
  const float* x    = (const float*)d_in[0];
  const int*   eidx = (const int*)d_in[1];
  const float* ewt  = (const float*)d_in[2];
  const float* gate = (const float*)d_in[3];
  const float* up   = (const float*)d_in[4];
  const float* down = (const float*)d_in[5];
  float* out = (float*)d_out;
  char* ws = (char*)d_ws;

  constexpr size_t OFF_INTERM = 0;                                  // 8192*4096*2 = 64 MiB
  constexpr size_t OFF_XB     = (size_t)NASS * ID * 2;              // + 4096*1024*2 = 8 MiB
  constexpr size_t OFF_META   = OFF_XB + (size_t)NTOK * HD * 2;
  constexpr size_t OFF_TOK    = OFF_META + 256;
  constexpr size_t OFF_WT     = OFF_TOK + (size_t)NASS * 4;

  u16* interm  = (u16*)(ws + OFF_INTERM);
  u16* xb      = (u16*)(ws + OFF_XB);
  int* counts  = (int*)(ws + OFF_META);
  int* cursors = (int*)(ws + OFF_META + 64);
  int* offsets = (int*)(ws + OFF_META + 128);
  int* tokl    = (int*)(ws + OFF_TOK);
  float* wtl   = (float*)(ws + OFF_WT);

  k_prep<<<dim3((NTOK * HD / 8) / 256), dim3(256), 0, stream>>>(x, xb, out, counts, cursors);
  k_count<<<dim3(NASS / 256), dim3(256), 0, stream>>>(eidx, counts);
  k_scan<<<dim3(1), dim3(64), 0, stream>>>(counts, offsets);
  k_place<<<dim3(NASS / 256), dim3(256), 0, stream>>>(eidx, ewt, offsets, cursors, tokl, wtl);
  k_gemm1<<<dim3(ID / 64, 64, NE), dim3(256), 0, stream>>>(xb, gate, up, offsets, tokl, interm);
  k_gemm2<<<dim3(HD / 64, 64, NE), dim3(256), 0, stream>>>(interm, down, offsets, tokl, wtl, out);
}

// Round 2
// 619.086 us; speedup vs baseline: 1.0453x; 1.0453x over previous
//
#include <hip/hip_runtime.h>
#include <hip/hip_bf16.h>
#include <cstdint>

#define HD 1024
#define ID 4096
#define NE 8
#define NTOK 4096
#define NASS 8192

typedef unsigned short u16;
typedef __attribute__((ext_vector_type(8))) __bf16 bf16x8;
typedef __attribute__((ext_vector_type(4))) float f32x4;

__device__ __forceinline__ void async16(void* lds, const void* g) {
  __builtin_amdgcn_global_load_lds(
      (const __attribute__((address_space(1))) uint32_t*)g,
      (__attribute__((address_space(3))) uint32_t*)lds, 16, 0, 0);
}

__device__ __forceinline__ u16 f2b(float f) {
  __bf16 h = (__bf16)f;
  return __builtin_bit_cast(u16, h);
}

__device__ __forceinline__ bf16x8 cvt8(const float* p) {
  const float4* q = (const float4*)p;
  float4 a = q[0], b = q[1];
  bf16x8 v;
  v[0] = (__bf16)a.x; v[1] = (__bf16)a.y; v[2] = (__bf16)a.z; v[3] = (__bf16)a.w;
  v[4] = (__bf16)b.x; v[5] = (__bf16)b.y; v[6] = (__bf16)b.z; v[7] = (__bf16)b.w;
  return v;
}

// ---- prep: x fp32 -> bf16, zero out ----
__global__ void k_prep(const float* __restrict__ x, u16* __restrict__ xb,
                       float* __restrict__ out) {
  int gid = blockIdx.x * 256 + threadIdx.x;
  size_t i8 = (size_t)gid * 8;
  *(bf16x8*)(xb + i8) = cvt8(x + i8);
  float4 z = {0.f, 0.f, 0.f, 0.f};
  float4* op = (float4*)(out + i8);
  op[0] = z; op[1] = z;
}

// ---- weight conversion: fp32 -> bf16 (BW-bound, 604 MB) ----
__global__ void k_wconv(const float* __restrict__ g, const float* __restrict__ u,
                        const float* __restrict__ d, u16* __restrict__ wg,
                        u16* __restrict__ wu, u16* __restrict__ wd) {
  size_t gid = (size_t)blockIdx.x * 256 + threadIdx.x;  // vec8 index
  const float* src; u16* dst; size_t off;
  if (gid < 4194304ull)      { src = g; dst = wg; off = gid; }
  else if (gid < 8388608ull) { src = u; dst = wu; off = gid - 4194304ull; }
  else                       { src = d; dst = wd; off = gid - 8388608ull; }
  size_t i8 = off * 8;
  *(bf16x8*)(dst + i8) = cvt8(src + i8);
}

// ---- fused count + scan + place (single block) ----
__global__ void k_meta(const int* __restrict__ eidx, const float* __restrict__ ewt,
                       int* __restrict__ offsets, int* __restrict__ tokl,
                       float* __restrict__ wtl) {
  __shared__ int cnt[NE], offs_s[NE + 1], cur[NE];
  int t = threadIdx.x;
  if (t < NE) cnt[t] = 0;
  __syncthreads();
  for (int i = t; i < NASS; i += 1024) atomicAdd(&cnt[eidx[i]], 1);
  __syncthreads();
  if (t == 0) {
    int s = 0;
    for (int e = 0; e < NE; ++e) { offs_s[e] = s; s += cnt[e]; }
    offs_s[NE] = s;
  }
  if (t < NE) cur[t] = 0;
  __syncthreads();
  for (int i = t; i < NASS; i += 1024) {
    int e = eidx[i];
    int p = atomicAdd(&cur[e], 1);
    int row = offs_s[e] + p;
    tokl[row] = i >> 1;
    wtl[row] = ewt[i];
  }
  if (t <= NE) offsets[t] = offs_s[t];
}

// ---- GEMM1 (primary): interm = silu(X@G^T)*(X@U^T), bf16 weights, all gload_lds ----
// BM=128, BN=64 dual (gate+up), BK=64, 4 waves (2x2)
__global__ __launch_bounds__(256) void k_gemm1(
    const u16* __restrict__ xb, const u16* __restrict__ wg, const u16* __restrict__ wu,
    const int* __restrict__ offsets, const int* __restrict__ tokl,
    u16* __restrict__ interm) {
  const int e = blockIdx.z;
  const int offs = offsets[e];
  const int Me = offsets[e + 1] - offs;
  const int m0 = blockIdx.y * 128;
  if (m0 >= Me) return;
  const int n0 = blockIdx.x * 64;
  const int t = threadIdx.x, lane = t & 63, wv = t >> 6;
  const int wm = wv & 1, wn = wv >> 1;

  __shared__ __align__(16) u16 As[128 * 64];
  __shared__ __align__(16) u16 Bg[64 * 64];
  __shared__ __align__(16) u16 Bu[64 * 64];

  const u16* asrc[4];
#pragma unroll
  for (int p = 0; p < 4; ++p) {
    int c = p * 256 + t;
    int r = c >> 3, c8 = c & 7;
    int row = m0 + r; if (row > Me - 1) row = Me - 1;
    asrc[p] = xb + (size_t)tokl[offs + row] * HD + c8 * 8;
  }
  const u16 *bgsrc[2], *busrc[2];
#pragma unroll
  for (int q = 0; q < 2; ++q) {
    int c = q * 256 + t;
    int r = c >> 3, c8 = c & 7;
    size_t boff = ((size_t)e * ID + n0 + r) * HD + c8 * 8;
    bgsrc[q] = wg + boff;
    busrc[q] = wu + boff;
  }

  f32x4 accg[4][2], accu[4][2];
#pragma unroll
  for (int mi = 0; mi < 4; ++mi)
#pragma unroll
    for (int ni = 0; ni < 2; ++ni) {
      accg[mi][ni] = (f32x4){0.f, 0.f, 0.f, 0.f};
      accu[mi][ni] = (f32x4){0.f, 0.f, 0.f, 0.f};
    }

  const int lrow = lane & 15, lk = (lane >> 4) * 8;
#pragma unroll 1
  for (int ks = 0; ks < HD / 64; ++ks) {
    __syncthreads();
#pragma unroll
    for (int p = 0; p < 4; ++p)
      async16((char*)As + (p * 256 + wv * 64) * 16, asrc[p]);
#pragma unroll
    for (int q = 0; q < 2; ++q) {
      async16((char*)Bg + (q * 256 + wv * 64) * 16, bgsrc[q]);
      async16((char*)Bu + (q * 256 + wv * 64) * 16, busrc[q]);
    }
    __syncthreads();
#pragma unroll
    for (int kk = 0; kk < 2; ++kk) {
      bf16x8 af[4], bg[2], bu[2];
#pragma unroll
      for (int mi = 0; mi < 4; ++mi)
        af[mi] = *(const bf16x8*)&As[(wm * 64 + mi * 16 + lrow) * 64 + kk * 32 + lk];
#pragma unroll
      for (int ni = 0; ni < 2; ++ni) {
        bg[ni] = *(const bf16x8*)&Bg[(wn * 32 + ni * 16 + lrow) * 64 + kk * 32 + lk];
        bu[ni] = *(const bf16x8*)&Bu[(wn * 32 + ni * 16 + lrow) * 64 + kk * 32 + lk];
      }
#pragma unroll
      for (int mi = 0; mi < 4; ++mi)
#pragma unroll
        for (int ni = 0; ni < 2; ++ni) {
          accg[mi][ni] = __builtin_amdgcn_mfma_f32_16x16x32_bf16(af[mi], bg[ni], accg[mi][ni], 0, 0, 0);
          accu[mi][ni] = __builtin_amdgcn_mfma_f32_16x16x32_bf16(af[mi], bu[ni], accu[mi][ni], 0, 0, 0);
        }
    }
#pragma unroll
    for (int p = 0; p < 4; ++p) asrc[p] += 64;
    bgsrc[0] += 64; bgsrc[1] += 64; busrc[0] += 64; busrc[1] += 64;
  }

#pragma unroll
  for (int mi = 0; mi < 4; ++mi) {
    int rb = wm * 64 + mi * 16 + (lane >> 4) * 4;
#pragma unroll
    for (int ni = 0; ni < 2; ++ni) {
      int col = n0 + wn * 32 + ni * 16 + (lane & 15);
#pragma unroll
      for (int j = 0; j < 4; ++j) {
        int row = m0 + rb + j;
        if (row < Me) {
          float g = accg[mi][ni][j], u = accu[mi][ni][j];
          float s = g / (1.f + __expf(-g));
          interm[(size_t)(offs + row) * ID + col] = f2b(s * u);
        }
      }
    }
  }
}

// ---- GEMM2 (primary): out += wt * (interm @ D^T), bf16 weights, BM=128 BN=128 ----
__global__ __launch_bounds__(256) void k_gemm2(
    const u16* __restrict__ interm, const u16* __restrict__ wd,
    const int* __restrict__ offsets, const int* __restrict__ tokl,
    const float* __restrict__ wtl, float* __restrict__ out) {
  const int e = blockIdx.z;
  const int offs = offsets[e];
  const int Me = offsets[e + 1] - offs;
  const int m0 = blockIdx.y * 128;
  if (m0 >= Me) return;
  const int n0 = blockIdx.x * 128;
  const int t = threadIdx.x, lane = t & 63, wv = t >> 6;
  const int wm = wv & 1, wn = wv >> 1;

  __shared__ __align__(16) u16 As[128 * 64];
  __shared__ __align__(16) u16 Bs[128 * 64];

  const u16* asrc[4];
#pragma unroll
  for (int p = 0; p < 4; ++p) {
    int c = p * 256 + t;
    int r = c >> 3, c8 = c & 7;
    int row = m0 + r; if (row > Me - 1) row = Me - 1;
    asrc[p] = interm + (size_t)(offs + row) * ID + c8 * 8;
  }
  const u16* bsrc[4];
#pragma unroll
  for (int p = 0; p < 4; ++p) {
    int c = p * 256 + t;
    int r = c >> 3, c8 = c & 7;
    bsrc[p] = wd + ((size_t)e * HD + n0 + r) * ID + c8 * 8;
  }

  f32x4 acc[4][4];
#pragma unroll
  for (int mi = 0; mi < 4; ++mi)
#pragma unroll
    for (int ni = 0; ni < 4; ++ni) acc[mi][ni] = (f32x4){0.f, 0.f, 0.f, 0.f};

  const int lrow = lane & 15, lk = (lane >> 4) * 8;
#pragma unroll 1
  for (int ks = 0; ks < ID / 64; ++ks) {
    __syncthreads();
#pragma unroll
    for (int p = 0; p < 4; ++p)
      async16((char*)As + (p * 256 + wv * 64) * 16, asrc[p]);
#pragma unroll
    for (int p = 0; p < 4; ++p)
      async16((char*)Bs + (p * 256 + wv * 64) * 16, bsrc[p]);
    __syncthreads();
#pragma unroll
    for (int kk = 0; kk < 2; ++kk) {
      bf16x8 af[4], bfr[4];
#pragma unroll
      for (int mi = 0; mi < 4; ++mi)
        af[mi] = *(const bf16x8*)&As[(wm * 64 + mi * 16 + lrow) * 64 + kk * 32 + lk];
#pragma unroll
      for (int ni = 0; ni < 4; ++ni)
        bfr[ni] = *(const bf16x8*)&Bs[(wn * 64 + ni * 16 + lrow) * 64 + kk * 32 + lk];
#pragma unroll
      for (int mi = 0; mi < 4; ++mi)
#pragma unroll
        for (int ni = 0; ni < 4; ++ni)
          acc[mi][ni] = __builtin_amdgcn_mfma_f32_16x16x32_bf16(af[mi], bfr[ni], acc[mi][ni], 0, 0, 0);
    }
#pragma unroll
    for (int p = 0; p < 4; ++p) { asrc[p] += 64; bsrc[p] += 64; }
  }

#pragma unroll
  for (int mi = 0; mi < 4; ++mi) {
    int rb = wm * 64 + mi * 16 + (lane >> 4) * 4;
#pragma unroll
    for (int ni = 0; ni < 4; ++ni) {
      int col = n0 + wn * 64 + ni * 16 + (lane & 15);
#pragma unroll
      for (int j = 0; j < 4; ++j) {
        int row = m0 + rb + j;
        if (row < Me) {
          int grow = offs + row;
          atomicAdd(out + (size_t)tokl[grow] * HD + col, wtl[grow] * acc[mi][ni][j]);
        }
      }
    }
  }
}

// ================= fallback path (fp32 weights on the fly, round-1 kernels) ==========
__global__ __launch_bounds__(256) void k_gemm1_f(
    const u16* __restrict__ xb, const float* __restrict__ gate,
    const float* __restrict__ up, const int* __restrict__ offsets,
    const int* __restrict__ tokl, u16* __restrict__ interm) {
  const int e = blockIdx.z;
  const int offs = offsets[e];
  const int Me = offsets[e + 1] - offs;
  const int m0 = blockIdx.y * 128;
  if (m0 >= Me) return;
  const int n0 = blockIdx.x * 64;
  const int t = threadIdx.x, lane = t & 63, wv = t >> 6;
  const int wm = wv & 1, wn = wv >> 1;
  __shared__ __align__(16) u16 As[128 * 64];
  __shared__ __align__(16) u16 Bg[64 * 64];
  __shared__ __align__(16) u16 Bu[64 * 64];
  const u16* asrc[4];
#pragma unroll
  for (int p = 0; p < 4; ++p) {
    int c = p * 256 + t;
    int r = c >> 3, c8 = c & 7;
    int row = m0 + r; if (row > Me - 1) row = Me - 1;
    asrc[p] = xb + (size_t)tokl[offs + row] * HD + c8 * 8;
  }
  const float *gsrc[2], *usrc[2];
#pragma unroll
  for (int q = 0; q < 2; ++q) {
    int c = q * 256 + t;
    int r = c >> 3, c8 = c & 7;
    size_t boff = ((size_t)e * ID + n0 + r) * HD + c8 * 8;
    gsrc[q] = gate + boff;
    usrc[q] = up + boff;
  }
  f32x4 accg[4][2], accu[4][2];
#pragma unroll
  for (int mi = 0; mi < 4; ++mi)
#pragma unroll
    for (int ni = 0; ni < 2; ++ni) {
      accg[mi][ni] = (f32x4){0.f, 0.f, 0.f, 0.f};
      accu[mi][ni] = (f32x4){0.f, 0.f, 0.f, 0.f};
    }
  const int lrow = lane & 15, lk = (lane >> 4) * 8;
#pragma unroll 1
  for (int ks = 0; ks < HD / 64; ++ks) {
    __syncthreads();
#pragma unroll
    for (int p = 0; p < 4; ++p)
      async16((char*)As + (p * 256 + wv * 64) * 16, asrc[p]);
#pragma unroll
    for (int q = 0; q < 2; ++q) {
      bf16x8 vg = cvt8(gsrc[q]);
      bf16x8 vu = cvt8(usrc[q]);
      *(bf16x8*)((char*)Bg + (q * 256 + t) * 16) = vg;
      *(bf16x8*)((char*)Bu + (q * 256 + t) * 16) = vu;
    }
    __syncthreads();
#pragma unroll
    for (int kk = 0; kk < 2; ++kk) {
      bf16x8 af[4], bg[2], bu[2];
#pragma unroll
      for (int mi = 0; mi < 4; ++mi)
        af[mi] = *(const bf16x8*)&As[(wm * 64 + mi * 16 + lrow) * 64 + kk * 32 + lk];
#pragma unroll
      for (int ni = 0; ni < 2; ++ni) {
        bg[ni] = *(const bf16x8*)&Bg[(wn * 32 + ni * 16 + lrow) * 64 + kk * 32 + lk];
        bu[ni] = *(const bf16x8*)&Bu[(wn * 32 + ni * 16 + lrow) * 64 + kk * 32 + lk];
      }
#pragma unroll
      for (int mi = 0; mi < 4; ++mi)
#pragma unroll
        for (int ni = 0; ni < 2; ++ni) {
          accg[mi][ni] = __builtin_amdgcn_mfma_f32_16x16x32_bf16(af[mi], bg[ni], accg[mi][ni], 0, 0, 0);
          accu[mi][ni] = __builtin_amdgcn_mfma_f32_16x16x32_bf16(af[mi], bu[ni], accu[mi][ni], 0, 0, 0);
        }
    }
#pragma unroll
    for (int p = 0; p < 4; ++p) asrc[p] += 64;
    gsrc[0] += 64; gsrc[1] += 64; usrc[0] += 64; usrc[1] += 64;
  }
#pragma unroll
  for (int mi = 0; mi < 4; ++mi) {
    int rb = wm * 64 + mi * 16 + (lane >> 4) * 4;
#pragma unroll
    for (int ni = 0; ni < 2; ++ni) {
      int col = n0 + wn * 32 + ni * 16 + (lane & 15);
#pragma unroll
      for (int j = 0; j < 4; ++j) {
        int row = m0 + rb + j;
        if (row < Me) {
          float g = accg[mi][ni][j], u = accu[mi][ni][j];
          float s = g / (1.f + __expf(-g));
          interm[(size_t)(offs + row) * ID + col] = f2b(s * u);
        }
      }
    }
  }
}

__global__ __launch_bounds__(256) void k_gemm2_f(
    const u16* __restrict__ interm, const float* __restrict__ down,
    const int* __restrict__ offsets, const int* __restrict__ tokl,
    const float* __restrict__ wtl, float* __restrict__ out) {
  const int e = blockIdx.z;
  const int offs = offsets[e];
  const int Me = offsets[e + 1] - offs;
  const int m0 = blockIdx.y * 128;
  if (m0 >= Me) return;
  const int n0 = blockIdx.x * 64;
  const int t = threadIdx.x, lane = t & 63, wv = t >> 6;
  const int wm = wv & 1, wn = wv >> 1;
  __shared__ __align__(16) u16 As[128 * 64];
  __shared__ __align__(16) u16 Bs[64 * 64];
  const u16* asrc[4];
#pragma unroll
  for (int p = 0; p < 4; ++p) {
    int c = p * 256 + t;
    int r = c >> 3, c8 = c & 7;
    int row = m0 + r; if (row > Me - 1) row = Me - 1;
    asrc[p] = interm + (size_t)(offs + row) * ID + c8 * 8;
  }
  const float* bsrc[2];
#pragma unroll
  for (int q = 0; q < 2; ++q) {
    int c = q * 256 + t;
    int r = c >> 3, c8 = c & 7;
    bsrc[q] = down + ((size_t)e * HD + n0 + r) * ID + c8 * 8;
  }
  f32x4 acc[4][2];
#pragma unroll
  for (int mi = 0; mi < 4; ++mi)
#pragma unroll
    for (int ni = 0; ni < 2; ++ni) acc[mi][ni] = (f32x4){0.f, 0.f, 0.f, 0.f};
  const int lrow = lane & 15, lk = (lane >> 4) * 8;
#pragma unroll 1
  for (int ks = 0; ks < ID / 64; ++ks) {
    __syncthreads();
#pragma unroll
    for (int p = 0; p < 4; ++p)
      async16((char*)As + (p * 256 + wv * 64) * 16, asrc[p]);
#pragma unroll
    for (int q = 0; q < 2; ++q)
      *(bf16x8*)((char*)Bs + (q * 256 + t) * 16) = cvt8(bsrc[q]);
    __syncthreads();
#pragma unroll
    for (int kk = 0; kk < 2; ++kk) {
      bf16x8 af[4], bfr[2];
#pragma unroll
      for (int mi = 0; mi < 4; ++mi)
        af[mi] = *(const bf16x8*)&As[(wm * 64 + mi * 16 + lrow) * 64 + kk * 32 + lk];
#pragma unroll
      for (int ni = 0; ni < 2; ++ni)
        bfr[ni] = *(const bf16x8*)&Bs[(wn * 32 + ni * 16 + lrow) * 64 + kk * 32 + lk];
#pragma unroll
      for (int mi = 0; mi < 4; ++mi)
#pragma unroll
        for (int ni = 0; ni < 2; ++ni)
          acc[mi][ni] = __builtin_amdgcn_mfma_f32_16x16x32_bf16(af[mi], bfr[ni], acc[mi][ni], 0, 0, 0);
    }
#pragma unroll
    for (int p = 0; p < 4; ++p) asrc[p] += 64;
    bsrc[0] += 64; bsrc[1] += 64;
  }
#pragma unroll
  for (int mi = 0; mi < 4; ++mi) {
    int rb = wm * 64 + mi * 16 + (lane >> 4) * 4;
#pragma unroll
    for (int ni = 0; ni < 2; ++ni) {
      int col = n0 + wn * 32 + ni * 16 + (lane & 15);
#pragma unroll
      for (int j = 0; j < 4; ++j) {
        int row = m0 + rb + j;
        if (row < Me) {
          int grow = offs + row;
          atomicAdd(out + (size_t)tokl[grow] * HD + col, wtl[grow] * acc[mi][ni][j]);
        }
      }
    }
  }
}

extern "C" void kernel_launch(void* const* d_in, const int* in_sizes, int n_in,
                              void* d_out, int out_size, void* d_ws, size_t ws_size,
                              hipStream_t stream) {
  const float* x    = (const float*)d_in[0];
  const int*   eidx = (const int*)d_in[1];
  const float* ewt  = (const float*)d_in[2];
  const float* gate = (const float*)d_in[3];
  const float* up   = (const float*)d_in[4];
  const float* down = (const float*)d_in[5];
  float* out = (float*)d_out;
  char* ws = (char*)d_ws;

  constexpr size_t OFF_INTERM = 0;                       // 67,108,864
  constexpr size_t OFF_XB     = 67108864;                // + 8,388,608
  constexpr size_t OFF_META   = 75497472;                // offsets[9]
  constexpr size_t OFF_TOK    = 75497728;                // 32 KiB
  constexpr size_t OFF_WT     = 75530496;                // 32 KiB
  constexpr size_t OFF_WG     = 75563264;                // 64 MiB
  constexpr size_t OFF_WU     = 142672128;               // 64 MiB
  constexpr size_t OFF_WD     = 209780992;               // 64 MiB
  constexpr size_t NEED_FULL  = 276889856;

  u16* interm  = (u16*)(ws + OFF_INTERM);
  u16* xb      = (u16*)(ws + OFF_XB);
  int* offsets = (int*)(ws + OFF_META);
  int* tokl    = (int*)(ws + OFF_TOK);
  float* wtl   = (float*)(ws + OFF_WT);
  u16* wg      = (u16*)(ws + OFF_WG);
  u16* wu      = (u16*)(ws + OFF_WU);
  u16* wd      = (u16*)(ws + OFF_WD);

  const bool full = ws_size >= NEED_FULL;

  k_prep<<<dim3((NTOK * HD / 8) / 256), dim3(256), 0, stream>>>(x, xb, out);
  k_meta<<<dim3(1), dim3(1024), 0, stream>>>(eidx, ewt, offsets, tokl, wtl);

  if (full) {
    k_wconv<<<dim3(49152), dim3(256), 0, stream>>>(gate, up, down, wg, wu, wd);
    k_gemm1<<<dim3(ID / 64, 64, NE), dim3(256), 0, stream>>>(xb, wg, wu, offsets, tokl, interm);
    k_gemm2<<<dim3(HD / 128, 64, NE), dim3(256), 0, stream>>>(interm, wd, offsets, tokl, wtl, out);
  } else {
    k_gemm1_f<<<dim3(ID / 64, 64, NE), dim3(256), 0, stream>>>(xb, gate, up, offsets, tokl, interm);
    k_gemm2_f<<<dim3(HD / 64, 64, NE), dim3(256), 0, stream>>>(interm, down, offsets, tokl, wtl, out);
  }
}